// Round 5
// baseline (300.573 us; speedup 1.0000x reference)
//
#include <hip/hip_runtime.h>

// B=2, C=64, D=32, HW=4096; heads=8, hd=8
#define SB   131072          // sites per batch = D*HW
#define CSTR 131072          // channel stride (elements)
#define BSTR 8388608         // batch stride (elements)

using u32x4  = __attribute__((ext_vector_type(4))) unsigned int;
using u32x2  = __attribute__((ext_vector_type(2))) unsigned int;
using bf16x8 = __attribute__((ext_vector_type(8))) short;   // MFMA A/B frag (4 VGPRs)
using f32x4  = __attribute__((ext_vector_type(4))) float;   // MFMA C/D frag
using f32x2  = __attribute__((ext_vector_type(2))) float;   // packed-f32 pair

// Single-instruction bf16 pair pack (RNE). No builtin on gfx950 -> inline asm.
__device__ __forceinline__ unsigned pack2(float a, float b) {
    unsigned r;
    asm("v_cvt_pk_bf16_f32 %0, %1, %2" : "=v"(r) : "v"(a), "v"(b));
    return r;
}
__device__ __forceinline__ float bflo(unsigned u) { return __uint_as_float(u << 16); }
__device__ __forceinline__ float bfhi(unsigned u) { return __uint_as_float(u & 0xffff0000u); }

__device__ __forceinline__ f32x4 mfma16(bf16x8 a, bf16x8 b, f32x4 c) {
    return __builtin_amdgcn_mfma_f32_16x16x32_bf16(a, b, c, 0, 0, 0);
}

// LDS tile swizzle: [site][64ch] bf16 rows are 128B -> naive ds_read_b128 at
// fixed channel is a same-bank pattern. XOR byte bits 4..6 with
// f(site) = (j ^ k ^ ((j&1)<<2)) & 7, j=site>>2, k=site&3.
// Hand-verified conflict-free on BOTH the write pattern (lanes (j,qd),
// cp=4i+qd -> bank = qd + 4*(i^f): 32 distinct) and the b128 read pattern
// (bank-quad = (qd+4kt)^f: 8 lanes per quad). Write/read use the same f.
__device__ __forceinline__ int swzf(int s) {
    return ((s >> 2) ^ (s & 3) ^ (((s >> 2) & 1) << 2)) & 7;
}

// Load 4 mtiles x 2 ktiles of A-fragments from a row-major fp32 [64][64] weight.
// A-frag layout (16x16x32): lane holds A[m = lane&15][k = quad*8 + j], j=0..7.
// Weight pairs are contiguous -> float2 loads + 1 cvt_pk each.
#define LOAD_A_FRAGS(A, W, n, qd)                                          \
    _Pragma("unroll")                                                      \
    for (int mt = 0; mt < 4; ++mt) {                                       \
        _Pragma("unroll")                                                  \
        for (int kt = 0; kt < 2; ++kt) {                                   \
            union { bf16x8 v; unsigned u[4]; } tw;                         \
            _Pragma("unroll")                                              \
            for (int r = 0; r < 4; ++r) {                                  \
                const int o = mt * 16 + (n);                               \
                const int c = kt * 32 + (qd) * 8 + 2 * r;                  \
                const float2 wv = *(const float2*)&W[o * 64 + c];          \
                tw.u[r] = pack2(wv.x, wv.y);                               \
            }                                                              \
            A[mt][kt] = tw.v;                                              \
        }                                                                  \
    }

// Stage this wave's 64-site x 64-ch x-tile into its LDS region as bf16
// [site][ch] with swizzle. Coalesced: per (i,qd) the 16 j-lanes read 256B
// contiguous float4 spans. 16 dwordx4 loads/lane replace 64 scalar dwords.
#define STAGE_X(ls, wbase, xb, tl, j, qd)                                  \
    _Pragma("unroll")                                                      \
    for (int i = 0; i < 8; ++i) {                                          \
        const int cp = i * 4 + (qd);                                       \
        const float4 x0 = *(const float4*)&(xb)[(size_t)(2 * cp) * CSTR + (tl) + 4 * (j)]; \
        const float4 x1 = *(const float4*)&(xb)[(size_t)(2 * cp + 1) * CSTR + (tl) + 4 * (j)]; \
        _Pragma("unroll")                                                  \
        for (int k = 0; k < 4; ++k) {                                      \
            const int s = 4 * (j) + k;                                     \
            (ls)[(wbase) + s * 32 + (cp ^ (swzf(s) << 2))] =               \
                pack2(((const float*)&x0)[k], ((const float*)&x1)[k]);     \
        }                                                                  \
    }

// B-frag read from staged LDS: 8 channels at one site = one ds_read_b128.
#define LDS_BFRAG(Bf, ls, wbase, t, n, qd)                                 \
    {                                                                      \
        const int s  = (t) * 16 + (n);                                     \
        const int fw = swzf(s) << 2;                                       \
        const int rb = (wbase) + s * 32;                                   \
        Bf[0] = *(const bf16x8*)&(ls)[rb + ((0 * 16 + (qd) * 4) ^ fw)];    \
        Bf[1] = *(const bf16x8*)&(ls)[rb + ((1 * 16 + (qd) * 4) ^ fw)];    \
    }

// ---------------- K1: fused Q | K,V projections (MFMA, LDS-staged) --------
// 2048 blocks x 256 thr; parity split: even blocks -> Q-path, odd -> KV-path.
// v2: activations staged through LDS (coalesced float4 global loads +
// swizzled [site][ch] bf16 tile + ds_read_b128 B-frags) -- replaces the
// round-4 latency-bound 4B channel gather (VALUBusy 5%, HBM 23%).
__global__ __launch_bounds__(256)
void k1_proj(const float* __restrict__ qf, const float* __restrict__ kf,
             const float* __restrict__ Wq, const float* __restrict__ Wk,
             const float* __restrict__ Wv, unsigned* __restrict__ Qs,
             unsigned* __restrict__ Ks, unsigned* __restrict__ Vs)
{
    __shared__ unsigned ls[8192];   // 4 waves x 2048 words (8KB each) = 32KB

    const int vbid = blockIdx.x >> 1;
    const int path = blockIdx.x & 1;                       // 0 = Q, 1 = KV
    const int wid  = (vbid * 256 + (int)threadIdx.x) >> 6; // 0..4095
    const int lane = threadIdx.x & 63;
    const int qd   = lane >> 4;
    const int n    = lane & 15;
    const int j    = lane & 15;      // staging lane decomposition
    const int S0   = wid * 64;
    const int b    = S0 >> 17;
    const int tl   = S0 & (SB - 1);
    const int wbase = ((int)threadIdx.x >> 6) * 2048;

    if (path == 0) {
        const float* xb = qf + (size_t)b * BSTR;
        STAGE_X(ls, wbase, xb, tl, j, qd)
        __syncthreads();

        bf16x8 A[4][2];
        LOAD_A_FRAGS(A, Wq, n, qd)

        #pragma unroll
        for (int t = 0; t < 4; ++t) {
            const int site = tl + t * 16 + n;
            bf16x8 Bf[2];
            LDS_BFRAG(Bf, ls, wbase, t, n, qd)
            f32x4 acc[4];
            #pragma unroll
            for (int mt = 0; mt < 4; ++mt) acc[mt] = (f32x4){0.f, 0.f, 0.f, 0.f};
            #pragma unroll
            for (int kt = 0; kt < 2; ++kt)
                #pragma unroll
                for (int mt = 0; mt < 4; ++mt)
                    acc[mt] = mfma16(A[mt][kt], Bf[kt], acc[mt]);
            // lane holds out-ch o = mt*16 + qd*4 + r for its site
            // packed record [b][h][site][8e]; quads 0+1 cover 256B densely
            #pragma unroll
            for (int mt = 0; mt < 4; ++mt) {
                const int h = 2 * mt + (qd >> 1);
                unsigned* dst = Qs + ((unsigned)(b * 8 + h) * SB + site) * 4 + (qd & 1) * 2;
                u32x2 w;
                w.x = pack2(acc[mt][0], acc[mt][1]);
                w.y = pack2(acc[mt][2], acc[mt][3]);
                *(u32x2*)dst = w;
            }
        }
    } else {
        const float* xb = kf + (size_t)b * BSTR;
        STAGE_X(ls, wbase, xb, tl, j, qd)
        __syncthreads();

        bf16x8 AK[4][2], AV[4][2];
        LOAD_A_FRAGS(AK, Wk, n, qd)
        LOAD_A_FRAGS(AV, Wv, n, qd)

        #pragma unroll
        for (int t = 0; t < 4; ++t) {
            const int site = tl + t * 16 + n;
            bf16x8 Bf[2];
            LDS_BFRAG(Bf, ls, wbase, t, n, qd)
            f32x4 aK[4], aV[4];
            #pragma unroll
            for (int mt = 0; mt < 4; ++mt) {
                aK[mt] = (f32x4){0.f, 0.f, 0.f, 0.f};
                aV[mt] = (f32x4){0.f, 0.f, 0.f, 0.f};
            }
            #pragma unroll
            for (int kt = 0; kt < 2; ++kt)
                #pragma unroll
                for (int mt = 0; mt < 4; ++mt) {
                    aK[mt] = mfma16(AK[mt][kt], Bf[kt], aK[mt]);
                    aV[mt] = mfma16(AV[mt][kt], Bf[kt], aV[mt]);
                }
            #pragma unroll
            for (int mt = 0; mt < 4; ++mt) {
                const int h = 2 * mt + (qd >> 1);
                const unsigned off = ((unsigned)(b * 8 + h) * SB + site) * 4 + (qd & 1) * 2;
                u32x2 wk2, wv2;
                wk2.x = pack2(aK[mt][0], aK[mt][1]);
                wk2.y = pack2(aK[mt][2], aK[mt][3]);
                wv2.x = pack2(aV[mt][0], aV[mt][1]);
                wv2.y = pack2(aV[mt][2], aV[mt][3]);
                *(u32x2*)(Ks + off) = wk2;
                *(u32x2*)(Vs + off) = wv2;
            }
        }
    }
}

// ---------------- K2: attention per (pos-window, head) ----------------
// block = 256 thr = 32 pos x 8 dq-threads. K,V tiles in LDS.
// v4 (round-3, VERIFIED 64us, VGPR 44, occ 33%, VALUBusy 71%):
// single-pass fused softmax -- p = exp2(qk); sum += p; cx += p*v.
// No min-waves cap (rounds 1-2: any cap -> scratch spill). Row pairs share
// every LDS read; f32x2 math for v_pk_fma_f32; unroll 4 bounds in-flight
// LDS loads. Max-subtraction dropped (sim*scale ~ N(0,1), exp exact f32).
// NOTE: Cs aliases Qs (pass 0 writes rows 0-15, pass 1 reads rows 16-31;
// disjoint -> no hazard).
__global__ __launch_bounds__(256)
void k2_attn(const u32x4* Qs, const u32x4* __restrict__ Ks,
             const u32x4* __restrict__ Vs, u32x4* Cs)
{
    __shared__ unsigned int kls[4096];  // [d'][pos] 16B each = 16KB
    __shared__ unsigned int vls[4096];  // 16KB

    const int blk = blockIdx.x;          // 2048 blocks
    const int h   = blk & 7;
    const int w   = blk >> 3;            // 0..255
    const int b   = w >> 7;
    const int pos0 = (w & 127) * 32;

    const int tid = threadIdx.x;
    const int pos = tid & 31;
    const int dqt = tid >> 5;            // 0..7

    const int base = (b * 8 + h) * SB;

    #pragma unroll
    for (int i = 0; i < 4; ++i) {
        const int idx = tid + i * 256;       // 0..1023
        const int dp = idx >> 5, pp = idx & 31;
        *(u32x4*)&kls[idx * 4] = Ks[base + dp * 4096 + pos0 + pp];
        *(u32x4*)&vls[idx * 4] = Vs[base + dp * 4096 + pos0 + pp];
    }
    __syncthreads();

    // 8^-0.5 * log2(e): fold softmax scale and exp->exp2 conversion into Q
    const float sc = 0.35355339059327373f * 1.4426950408889634f;

    #pragma unroll 1
    for (int p = 0; p < 2; ++p) {
        const int dq0 = dqt + 16 * p;            // row pair: dq0, dq0+8
        const u32x4 qa = Qs[base + dq0 * 4096 + pos0 + pos];
        const u32x4 qb = Qs[base + (dq0 + 8) * 4096 + pos0 + pos];
        f32x2 q2[8];
        q2[0] = (f32x2){bflo(qa.x) * sc, bflo(qb.x) * sc};
        q2[1] = (f32x2){bfhi(qa.x) * sc, bfhi(qb.x) * sc};
        q2[2] = (f32x2){bflo(qa.y) * sc, bflo(qb.y) * sc};
        q2[3] = (f32x2){bfhi(qa.y) * sc, bfhi(qb.y) * sc};
        q2[4] = (f32x2){bflo(qa.z) * sc, bflo(qb.z) * sc};
        q2[5] = (f32x2){bfhi(qa.z) * sc, bfhi(qb.z) * sc};
        q2[6] = (f32x2){bflo(qa.w) * sc, bflo(qb.w) * sc};
        q2[7] = (f32x2){bfhi(qa.w) * sc, bfhi(qb.w) * sc};

        f32x2 cx[8];
        #pragma unroll
        for (int e = 0; e < 8; ++e) cx[e] = (f32x2){0.f, 0.f};
        f32x2 sum2 = (f32x2){0.f, 0.f};

        #pragma unroll 4
        for (int dp = 0; dp < 32; ++dp) {
            const u32x4 kk = *(const u32x4*)&kls[(dp * 32 + pos) * 4];
            const u32x4 vv = *(const u32x4*)&vls[(dp * 32 + pos) * 4];
            // two shorter dependency chains, then join
            f32x2 accA = q2[0] * bflo(kk.x);
            f32x2 accB = q2[1] * bfhi(kk.x);
            accA += q2[2] * bflo(kk.y);
            accB += q2[3] * bfhi(kk.y);
            accA += q2[4] * bflo(kk.z);
            accB += q2[5] * bfhi(kk.z);
            accA += q2[6] * bflo(kk.w);
            accB += q2[7] * bfhi(kk.w);
            const f32x2 acc = accA + accB;
            f32x2 ex;
            ex.x = exp2f(acc.x);       // p = exp(sim*scale), unnormalized
            ex.y = exp2f(acc.y);
            sum2 += ex;
            cx[0] += ex * bflo(vv.x);
            cx[1] += ex * bfhi(vv.x);
            cx[2] += ex * bflo(vv.y);
            cx[3] += ex * bfhi(vv.y);
            cx[4] += ex * bflo(vv.z);
            cx[5] += ex * bfhi(vv.z);
            cx[6] += ex * bflo(vv.w);
            cx[7] += ex * bfhi(vv.w);
        }

        const f32x2 inv2 = (f32x2){1.0f / sum2.x, 1.0f / sum2.y};
        #pragma unroll
        for (int e = 0; e < 8; ++e) cx[e] *= inv2;

        u32x4 pa, pb;
        pa.x = pack2(cx[0].x, cx[1].x); pa.y = pack2(cx[2].x, cx[3].x);
        pa.z = pack2(cx[4].x, cx[5].x); pa.w = pack2(cx[6].x, cx[7].x);
        pb.x = pack2(cx[0].y, cx[1].y); pb.y = pack2(cx[2].y, cx[3].y);
        pb.z = pack2(cx[4].y, cx[5].y); pb.w = pack2(cx[6].y, cx[7].y);
        Cs[base + dq0 * 4096 + pos0 + pos] = pa;
        Cs[base + (dq0 + 8) * 4096 + pos0 + pos] = pb;
    }
}

// ---------------- K3: Wo projection (MFMA) ----------------
// B-frag = one dwordx4 ctx record, already bf16 in e-order. No conversion.
__global__ __launch_bounds__(256)
void k3_out(const u32x4* __restrict__ Cs, const float* __restrict__ Wo,
            float* __restrict__ out)
{
    const int wid  = (blockIdx.x * 256 + threadIdx.x) >> 6;
    const int lane = threadIdx.x & 63;
    const int qd   = lane >> 4;
    const int n    = lane & 15;
    const int S0   = wid * 64;
    const int b    = S0 >> 17;
    const int tl   = S0 & (SB - 1);

    bf16x8 A[4][2];
    LOAD_A_FRAGS(A, Wo, n, qd)

    #pragma unroll
    for (int t = 0; t < 4; ++t) {
        const int site = tl + t * 16 + n;
        bf16x8 Bf[2];
        #pragma unroll
        for (int kt = 0; kt < 2; ++kt) {
            // k = kt*32 + qd*8 + j  ->  c = h*8+e with h = kt*4+qd, e = j
            Bf[kt] = *(const bf16x8*)(Cs + (unsigned)(b * 8 + kt * 4 + qd) * SB + site);
        }
        f32x4 acc[4];
        #pragma unroll
        for (int mt = 0; mt < 4; ++mt) acc[mt] = (f32x4){0.f, 0.f, 0.f, 0.f};
        #pragma unroll
        for (int kt = 0; kt < 2; ++kt)
            #pragma unroll
            for (int mt = 0; mt < 4; ++mt)
                acc[mt] = mfma16(A[mt][kt], Bf[kt], acc[mt]);
        #pragma unroll
        for (int mt = 0; mt < 4; ++mt)
            #pragma unroll
            for (int r = 0; r < 4; ++r)
                out[(size_t)b * BSTR + (size_t)(mt * 16 + qd * 4 + r) * CSTR + site]
                    = acc[mt][r];
    }
}

extern "C" void kernel_launch(void* const* d_in, const int* in_sizes, int n_in,
                              void* d_out, int out_size, void* d_ws, size_t ws_size,
                              hipStream_t stream) {
    const float* qf = (const float*)d_in[0];
    const float* kf = (const float*)d_in[1];
    const float* Wq = (const float*)d_in[2];
    const float* Wk = (const float*)d_in[3];
    const float* Wv = (const float*)d_in[4];
    const float* Wo = (const float*)d_in[5];
    float* out = (float*)d_out;

    // scratch layout (bf16 records, 33.55MB each):
    //   ws:    Q (later overwritten in-place by ctx) | V     -> 67.1MB used
    //   d_out: K (33.55MB <= 64MB)  -> overwritten by K3's fp32 out (K dead)
    unsigned* Qs = (unsigned*)d_ws;
    unsigned* Vs = (unsigned*)((char*)d_ws + (size_t)33554432);
    unsigned* Ks = (unsigned*)d_out;

    hipLaunchKernelGGL(k1_proj, dim3(2048), dim3(256), 0, stream,
                       qf, kf, Wq, Wk, Wv, Qs, Ks, Vs);
    hipLaunchKernelGGL(k2_attn, dim3(2048), dim3(256), 0, stream,
                       (const u32x4*)Qs, (const u32x4*)Ks, (const u32x4*)Vs,
                       (u32x4*)Qs);
    hipLaunchKernelGGL(k3_out, dim3(1024), dim3(256), 0, stream,
                       (const u32x4*)Qs, Wo, out);
}

// Round 6
// 288.889 us; speedup vs baseline: 1.0404x; 1.0404x over previous
//
#include <hip/hip_runtime.h>

// B=2, C=64, D=32, HW=4096; heads=8, hd=8
#define SB   131072          // sites per batch = D*HW
#define CSTR 131072          // channel stride (elements)
#define BSTR 8388608         // batch stride (elements)

using u32x4  = __attribute__((ext_vector_type(4))) unsigned int;
using u32x2  = __attribute__((ext_vector_type(2))) unsigned int;
using bf16x8 = __attribute__((ext_vector_type(8))) short;   // MFMA A/B frag (4 VGPRs)
using f32x4  = __attribute__((ext_vector_type(4))) float;   // MFMA C/D frag
using f32x2  = __attribute__((ext_vector_type(2))) float;   // packed-f32 pair

// Single-instruction bf16 pair pack (RNE). No builtin on gfx950 -> inline asm.
__device__ __forceinline__ unsigned pack2(float a, float b) {
    unsigned r;
    asm("v_cvt_pk_bf16_f32 %0, %1, %2" : "=v"(r) : "v"(a), "v"(b));
    return r;
}
__device__ __forceinline__ float bflo(unsigned u) { return __uint_as_float(u << 16); }
__device__ __forceinline__ float bfhi(unsigned u) { return __uint_as_float(u & 0xffff0000u); }

__device__ __forceinline__ f32x4 mfma16(bf16x8 a, bf16x8 b, f32x4 c) {
    return __builtin_amdgcn_mfma_f32_16x16x32_bf16(a, b, c, 0, 0, 0);
}

// LDS tile swizzle: [site][64ch] bf16 rows are 128B. XOR byte bits 4..6 with
// f(site) = (j ^ k ^ ((j&1)<<2)) & 7, j=site>>2, k=site&3. (round-5 verified:
// read side reconstructs channel pairs consecutively since fw only touches
// word bits 2..4 and the b128 read spans word bits 0..1.)
__device__ __forceinline__ int swzf(int s) {
    return ((s >> 2) ^ (s & 3) ^ (((s >> 2) & 1) << 2)) & 7;
}

// ---- Round-6 core fix: BATCH loads, THEN convert. ----
// Previous structure (load -> pack2 -> ds_write -> load...) forced
// s_waitcnt vmcnt(0) between every load: ~16 serialized ~900ns HBM waits
// per wave = the measured ~15.7us/block. All macros below issue every
// independent load into a register array first (one wait), then convert.

// Load 4 mtiles x 2 ktiles of A-fragments from a row-major fp32 [64][64]
// weight. A-frag layout (16x16x32): lane holds A[m=lane&15][k=quad*8+j].
#define LOAD_A_FRAGS(A, W, n, qd)                                          \
    {                                                                      \
        float4 wr[16];                                                     \
        _Pragma("unroll")                                                  \
        for (int mt = 0; mt < 4; ++mt) {                                   \
            _Pragma("unroll")                                              \
            for (int kt = 0; kt < 2; ++kt) {                               \
                const int o = mt * 16 + (n);                               \
                const int c = kt * 32 + (qd) * 8;                          \
                wr[(mt * 2 + kt) * 2]     = *(const float4*)&W[o * 64 + c];     \
                wr[(mt * 2 + kt) * 2 + 1] = *(const float4*)&W[o * 64 + c + 4]; \
            }                                                              \
        }                                                                  \
        _Pragma("unroll")                                                  \
        for (int mt = 0; mt < 4; ++mt) {                                   \
            _Pragma("unroll")                                              \
            for (int kt = 0; kt < 2; ++kt) {                               \
                union { bf16x8 v; unsigned u[4]; } tw;                     \
                const float4 w0 = wr[(mt * 2 + kt) * 2];                   \
                const float4 w1 = wr[(mt * 2 + kt) * 2 + 1];               \
                tw.u[0] = pack2(w0.x, w0.y);                               \
                tw.u[1] = pack2(w0.z, w0.w);                               \
                tw.u[2] = pack2(w1.x, w1.y);                               \
                tw.u[3] = pack2(w1.z, w1.w);                               \
                A[mt][kt] = tw.v;                                          \
            }                                                              \
        }                                                                  \
    }

// Stage this wave's 64-site x 64-ch x-tile into LDS as swizzled bf16
// [site][ch]. Phase 1: ALL 16 dwordx4 loads into xr[] (one vmcnt wait).
// Phase 2: pack + ds_write.
#define STAGE_X(ls, wbase, xb, tl, j, qd)                                  \
    {                                                                      \
        float4 xr[16];                                                     \
        _Pragma("unroll")                                                  \
        for (int i = 0; i < 8; ++i) {                                      \
            const int cp = i * 4 + (qd);                                   \
            xr[2 * i]     = *(const float4*)&(xb)[(size_t)(2 * cp) * CSTR + (tl) + 4 * (j)]; \
            xr[2 * i + 1] = *(const float4*)&(xb)[(size_t)(2 * cp + 1) * CSTR + (tl) + 4 * (j)]; \
        }                                                                  \
        _Pragma("unroll")                                                  \
        for (int i = 0; i < 8; ++i) {                                      \
            const int cp = i * 4 + (qd);                                   \
            _Pragma("unroll")                                              \
            for (int k = 0; k < 4; ++k) {                                  \
                const int s = 4 * (j) + k;                                 \
                (ls)[(wbase) + s * 32 + (cp ^ (swzf(s) << 2))] =           \
                    pack2(((const float*)&xr[2 * i])[k],                   \
                          ((const float*)&xr[2 * i + 1])[k]);              \
            }                                                              \
        }                                                                  \
    }

// B-frag read from staged LDS: 8 channels at one site = one ds_read_b128.
#define LDS_BFRAG(Bf, ls, wbase, t, n, qd)                                 \
    {                                                                      \
        const int s  = (t) * 16 + (n);                                     \
        const int fw = swzf(s) << 2;                                       \
        const int rb = (wbase) + s * 32;                                   \
        Bf[0] = *(const bf16x8*)&(ls)[rb + ((0 * 16 + (qd) * 4) ^ fw)];    \
        Bf[1] = *(const bf16x8*)&(ls)[rb + ((1 * 16 + (qd) * 4) ^ fw)];    \
    }

// ---------------- K1: fused Q | K,V projections (MFMA, LDS-staged) --------
// 2048 blocks x 256 thr; parity split: even blocks -> Q-path, odd -> KV-path.
__global__ __launch_bounds__(256)
void k1_proj(const float* __restrict__ qf, const float* __restrict__ kf,
             const float* __restrict__ Wq, const float* __restrict__ Wk,
             const float* __restrict__ Wv, unsigned* __restrict__ Qs,
             unsigned* __restrict__ Ks, unsigned* __restrict__ Vs)
{
    __shared__ unsigned ls[8192];   // 4 waves x 2048 words (8KB each) = 32KB

    const int vbid = blockIdx.x >> 1;
    const int path = blockIdx.x & 1;                       // 0 = Q, 1 = KV
    const int wid  = (vbid * 256 + (int)threadIdx.x) >> 6; // 0..4095
    const int lane = threadIdx.x & 63;
    const int qd   = lane >> 4;
    const int n    = lane & 15;
    const int j    = lane & 15;      // staging lane decomposition
    const int S0   = wid * 64;
    const int b    = S0 >> 17;
    const int tl   = S0 & (SB - 1);
    const int wbase = ((int)threadIdx.x >> 6) * 2048;

    if (path == 0) {
        const float* xb = qf + (size_t)b * BSTR;
        STAGE_X(ls, wbase, xb, tl, j, qd)

        bf16x8 A[4][2];
        LOAD_A_FRAGS(A, Wq, n, qd)
        __syncthreads();

        #pragma unroll
        for (int t = 0; t < 4; ++t) {
            const int site = tl + t * 16 + n;
            bf16x8 Bf[2];
            LDS_BFRAG(Bf, ls, wbase, t, n, qd)
            f32x4 acc[4];
            #pragma unroll
            for (int mt = 0; mt < 4; ++mt) acc[mt] = (f32x4){0.f, 0.f, 0.f, 0.f};
            #pragma unroll
            for (int kt = 0; kt < 2; ++kt)
                #pragma unroll
                for (int mt = 0; mt < 4; ++mt)
                    acc[mt] = mfma16(A[mt][kt], Bf[kt], acc[mt]);
            // lane holds out-ch o = mt*16 + qd*4 + r for its site
            // packed record [b][h][site][8e]; quads 0+1 cover 256B densely
            #pragma unroll
            for (int mt = 0; mt < 4; ++mt) {
                const int h = 2 * mt + (qd >> 1);
                unsigned* dst = Qs + ((unsigned)(b * 8 + h) * SB + site) * 4 + (qd & 1) * 2;
                u32x2 w;
                w.x = pack2(acc[mt][0], acc[mt][1]);
                w.y = pack2(acc[mt][2], acc[mt][3]);
                *(u32x2*)dst = w;
            }
        }
    } else {
        const float* xb = kf + (size_t)b * BSTR;
        STAGE_X(ls, wbase, xb, tl, j, qd)

        bf16x8 AK[4][2], AV[4][2];
        LOAD_A_FRAGS(AK, Wk, n, qd)
        LOAD_A_FRAGS(AV, Wv, n, qd)
        __syncthreads();

        #pragma unroll
        for (int t = 0; t < 4; ++t) {
            const int site = tl + t * 16 + n;
            bf16x8 Bf[2];
            LDS_BFRAG(Bf, ls, wbase, t, n, qd)
            f32x4 aK[4], aV[4];
            #pragma unroll
            for (int mt = 0; mt < 4; ++mt) {
                aK[mt] = (f32x4){0.f, 0.f, 0.f, 0.f};
                aV[mt] = (f32x4){0.f, 0.f, 0.f, 0.f};
            }
            #pragma unroll
            for (int kt = 0; kt < 2; ++kt)
                #pragma unroll
                for (int mt = 0; mt < 4; ++mt) {
                    aK[mt] = mfma16(AK[mt][kt], Bf[kt], aK[mt]);
                    aV[mt] = mfma16(AV[mt][kt], Bf[kt], aV[mt]);
                }
            #pragma unroll
            for (int mt = 0; mt < 4; ++mt) {
                const int h = 2 * mt + (qd >> 1);
                const unsigned off = ((unsigned)(b * 8 + h) * SB + site) * 4 + (qd & 1) * 2;
                u32x2 wk2, wv2;
                wk2.x = pack2(aK[mt][0], aK[mt][1]);
                wk2.y = pack2(aK[mt][2], aK[mt][3]);
                wv2.x = pack2(aV[mt][0], aV[mt][1]);
                wv2.y = pack2(aV[mt][2], aV[mt][3]);
                *(u32x2*)(Ks + off) = wk2;
                *(u32x2*)(Vs + off) = wv2;
            }
        }
    }
}

// ---------------- K2: attention per (pos-window, head) ----------------
// block = 256 thr = 32 pos x 8 dq-threads. K,V tiles in LDS.
// v4 (round-3, VERIFIED 64us, VGPR 44, occ 33%, VALUBusy 71%):
// single-pass fused softmax -- p = exp2(qk); sum += p; cx += p*v.
// No min-waves cap (rounds 1-2: any cap -> scratch spill). Row pairs share
// every LDS read; f32x2 math for v_pk_fma_f32; unroll 4 bounds in-flight
// LDS loads. Max-subtraction dropped (sim*scale ~ N(0,1), exp exact f32).
// NOTE: Cs aliases Qs (pass 0 writes rows 0-15, pass 1 reads rows 16-31;
// disjoint -> no hazard).
__global__ __launch_bounds__(256)
void k2_attn(const u32x4* Qs, const u32x4* __restrict__ Ks,
             const u32x4* __restrict__ Vs, u32x4* Cs)
{
    __shared__ unsigned int kls[4096];  // [d'][pos] 16B each = 16KB
    __shared__ unsigned int vls[4096];  // 16KB

    const int blk = blockIdx.x;          // 2048 blocks
    const int h   = blk & 7;
    const int w   = blk >> 3;            // 0..255
    const int b   = w >> 7;
    const int pos0 = (w & 127) * 32;

    const int tid = threadIdx.x;
    const int pos = tid & 31;
    const int dqt = tid >> 5;            // 0..7

    const int base = (b * 8 + h) * SB;

    #pragma unroll
    for (int i = 0; i < 4; ++i) {
        const int idx = tid + i * 256;       // 0..1023
        const int dp = idx >> 5, pp = idx & 31;
        *(u32x4*)&kls[idx * 4] = Ks[base + dp * 4096 + pos0 + pp];
        *(u32x4*)&vls[idx * 4] = Vs[base + dp * 4096 + pos0 + pp];
    }
    __syncthreads();

    // 8^-0.5 * log2(e): fold softmax scale and exp->exp2 conversion into Q
    const float sc = 0.35355339059327373f * 1.4426950408889634f;

    #pragma unroll 1
    for (int p = 0; p < 2; ++p) {
        const int dq0 = dqt + 16 * p;            // row pair: dq0, dq0+8
        const u32x4 qa = Qs[base + dq0 * 4096 + pos0 + pos];
        const u32x4 qb = Qs[base + (dq0 + 8) * 4096 + pos0 + pos];
        f32x2 q2[8];
        q2[0] = (f32x2){bflo(qa.x) * sc, bflo(qb.x) * sc};
        q2[1] = (f32x2){bfhi(qa.x) * sc, bfhi(qb.x) * sc};
        q2[2] = (f32x2){bflo(qa.y) * sc, bflo(qb.y) * sc};
        q2[3] = (f32x2){bfhi(qa.y) * sc, bfhi(qb.y) * sc};
        q2[4] = (f32x2){bflo(qa.z) * sc, bflo(qb.z) * sc};
        q2[5] = (f32x2){bfhi(qa.z) * sc, bfhi(qb.z) * sc};
        q2[6] = (f32x2){bflo(qa.w) * sc, bflo(qb.w) * sc};
        q2[7] = (f32x2){bfhi(qa.w) * sc, bfhi(qb.w) * sc};

        f32x2 cx[8];
        #pragma unroll
        for (int e = 0; e < 8; ++e) cx[e] = (f32x2){0.f, 0.f};
        f32x2 sum2 = (f32x2){0.f, 0.f};

        #pragma unroll 4
        for (int dp = 0; dp < 32; ++dp) {
            const u32x4 kk = *(const u32x4*)&kls[(dp * 32 + pos) * 4];
            const u32x4 vv = *(const u32x4*)&vls[(dp * 32 + pos) * 4];
            // two shorter dependency chains, then join
            f32x2 accA = q2[0] * bflo(kk.x);
            f32x2 accB = q2[1] * bfhi(kk.x);
            accA += q2[2] * bflo(kk.y);
            accB += q2[3] * bfhi(kk.y);
            accA += q2[4] * bflo(kk.z);
            accB += q2[5] * bfhi(kk.z);
            accA += q2[6] * bflo(kk.w);
            accB += q2[7] * bfhi(kk.w);
            const f32x2 acc = accA + accB;
            f32x2 ex;
            ex.x = exp2f(acc.x);       // p = exp(sim*scale), unnormalized
            ex.y = exp2f(acc.y);
            sum2 += ex;
            cx[0] += ex * bflo(vv.x);
            cx[1] += ex * bfhi(vv.x);
            cx[2] += ex * bflo(vv.y);
            cx[3] += ex * bfhi(vv.y);
            cx[4] += ex * bflo(vv.z);
            cx[5] += ex * bfhi(vv.z);
            cx[6] += ex * bflo(vv.w);
            cx[7] += ex * bfhi(vv.w);
        }

        const f32x2 inv2 = (f32x2){1.0f / sum2.x, 1.0f / sum2.y};
        #pragma unroll
        for (int e = 0; e < 8; ++e) cx[e] *= inv2;

        u32x4 pa, pb;
        pa.x = pack2(cx[0].x, cx[1].x); pa.y = pack2(cx[2].x, cx[3].x);
        pa.z = pack2(cx[4].x, cx[5].x); pa.w = pack2(cx[6].x, cx[7].x);
        pb.x = pack2(cx[0].y, cx[1].y); pb.y = pack2(cx[2].y, cx[3].y);
        pb.z = pack2(cx[4].y, cx[5].y); pb.w = pack2(cx[6].y, cx[7].y);
        Cs[base + dq0 * 4096 + pos0 + pos] = pa;
        Cs[base + (dq0 + 8) * 4096 + pos0 + pos] = pb;
    }
}

// ---------------- K3: Wo projection (MFMA) ----------------
// B-frag = one dwordx4 ctx record, already bf16 in e-order. No conversion.
// v2: ALL 8 ctx-frag loads batched before weights/MFMA (one vmcnt wait,
// was 8 serialized); weight loads batched inside LOAD_A_FRAGS.
__global__ __launch_bounds__(256)
void k3_out(const u32x4* __restrict__ Cs, const float* __restrict__ Wo,
            float* __restrict__ out)
{
    const int wid  = (blockIdx.x * 256 + threadIdx.x) >> 6;
    const int lane = threadIdx.x & 63;
    const int qd   = lane >> 4;
    const int n    = lane & 15;
    const int S0   = wid * 64;
    const int b    = S0 >> 17;
    const int tl   = S0 & (SB - 1);

    // batch the 8 cold ctx-frag loads first (k = kt*32+qd*8+j -> h=kt*4+qd)
    bf16x8 Bf[4][2];
    #pragma unroll
    for (int t = 0; t < 4; ++t) {
        const int site = tl + t * 16 + n;
        #pragma unroll
        for (int kt = 0; kt < 2; ++kt)
            Bf[t][kt] = *(const bf16x8*)(Cs + (unsigned)(b * 8 + kt * 4 + qd) * SB + site);
    }

    bf16x8 A[4][2];
    LOAD_A_FRAGS(A, Wo, n, qd)

    #pragma unroll
    for (int t = 0; t < 4; ++t) {
        const int site = tl + t * 16 + n;
        f32x4 acc[4];
        #pragma unroll
        for (int mt = 0; mt < 4; ++mt) acc[mt] = (f32x4){0.f, 0.f, 0.f, 0.f};
        #pragma unroll
        for (int kt = 0; kt < 2; ++kt)
            #pragma unroll
            for (int mt = 0; mt < 4; ++mt)
                acc[mt] = mfma16(A[mt][kt], Bf[t][kt], acc[mt]);
        #pragma unroll
        for (int mt = 0; mt < 4; ++mt)
            #pragma unroll
            for (int r = 0; r < 4; ++r)
                out[(size_t)b * BSTR + (size_t)(mt * 16 + qd * 4 + r) * CSTR + site]
                    = acc[mt][r];
    }
}

extern "C" void kernel_launch(void* const* d_in, const int* in_sizes, int n_in,
                              void* d_out, int out_size, void* d_ws, size_t ws_size,
                              hipStream_t stream) {
    const float* qf = (const float*)d_in[0];
    const float* kf = (const float*)d_in[1];
    const float* Wq = (const float*)d_in[2];
    const float* Wk = (const float*)d_in[3];
    const float* Wv = (const float*)d_in[4];
    const float* Wo = (const float*)d_in[5];
    float* out = (float*)d_out;

    // scratch layout (bf16 records, 33.55MB each):
    //   ws:    Q (later overwritten in-place by ctx) | V     -> 67.1MB used
    //   d_out: K (33.55MB <= 64MB)  -> overwritten by K3's fp32 out (K dead)
    unsigned* Qs = (unsigned*)d_ws;
    unsigned* Vs = (unsigned*)((char*)d_ws + (size_t)33554432);
    unsigned* Ks = (unsigned*)d_out;

    hipLaunchKernelGGL(k1_proj, dim3(2048), dim3(256), 0, stream,
                       qf, kf, Wq, Wk, Wv, Qs, Ks, Vs);
    hipLaunchKernelGGL(k2_attn, dim3(2048), dim3(256), 0, stream,
                       (const u32x4*)Qs, (const u32x4*)Ks, (const u32x4*)Vs,
                       (u32x4*)Qs);
    hipLaunchKernelGGL(k3_out, dim3(1024), dim3(256), 0, stream,
                       (const u32x4*)Qs, Wo, out);
}